// Round 7
// baseline (1327.438 us; speedup 1.0000x reference)
//
#include <hip/hip_runtime.h>
#include <stdint.h>

#define BB 64
#define PP 24656
#define CC 81
#define NEGPOS 3
#define RPT 16                     // rows per wave tile
#define TB (RPT * CC * 4)          // 5184 bytes
#define NT ((BB * PP) / RPT)       // 98624 tiles
#define TPB (PP / RPT)             // 1541 tiles per batch row
#define ROWS (BB * PP)
#define NSLOT 256
#define NBLK 1792                  // 7 blocks/CU
#define N4C 31954176L              // conf_data float4 count (ROWS*81/4)

typedef unsigned int u32;
typedef unsigned long long u64;

__device__ __forceinline__ void gload_lds16(const void* g, void* l) {
    __builtin_amdgcn_global_load_lds(
        (const __attribute__((address_space(1))) u32*)g,
        (__attribute__((address_space(3))) u32*)l, 16, 0, 0);
}
__device__ __forceinline__ void gload_lds4(const void* g, void* l) {
    __builtin_amdgcn_global_load_lds(
        (const __attribute__((address_space(1))) u32*)g,
        (__attribute__((address_space(3))) u32*)l, 4, 0, 0);
}

// ---------------- PROBE A: pure coalesced float4 streaming read ----------------
__global__ __launch_bounds__(256) void k_probe_read(
    const float4* __restrict__ src, long n4, int passes, float* __restrict__ sink)
{
    const long g = (long)blockIdx.x * 256 + threadIdx.x;
    const long G = (long)gridDim.x * 256;
    float s0 = 0.f, s1 = 0.f, s2 = 0.f, s3 = 0.f;
    for (int p = 0; p < passes; ++p) {
        long i = g;
        for (; i + 3 * G < n4; i += 4 * G) {
            const float4 v0 = src[i];
            const float4 v1 = src[i + G];
            const float4 v2 = src[i + 2 * G];
            const float4 v3 = src[i + 3 * G];
            s0 += v0.x + v0.y + v0.z + v0.w;
            s1 += v1.x + v1.y + v1.z + v1.w;
            s2 += v2.x + v2.y + v2.z + v2.w;
            s3 += v3.x + v3.y + v3.z + v3.w;
        }
        for (; i < n4; i += G) {
            const float4 v = src[i];
            s0 += v.x + v.y + v.z + v.w;
        }
    }
    sink[g] = s0 + s1 + s2 + s3;
}

// ---------------- PROBE C: R3's global_load_lds staging pattern, no compute ----
__global__ __launch_bounds__(256, 7) void k_probe_lds(
    const float* __restrict__ conf_data, int passes, float* __restrict__ sink)
{
    __shared__ __align__(16) float tile[4 * RPT * CC];
    const int t = threadIdx.x;
    const int w = t >> 6;
    const int lane = t & 63;
    char* wlds = (char*)(tile + w * (RPT * CC));
    const int wave_id = blockIdx.x * 4 + w;
    const int n_waves = NBLK * 4;
    float acc = 0.f;
    for (int p = 0; p < passes; ++p) {
        for (int td = wave_id; td < NT; td += n_waves) {
            const char* gb = (const char*)conf_data + (long)td * TB;
            asm volatile("s_waitcnt lgkmcnt(0)" ::: "memory");
            #pragma unroll
            for (int c = 0; c < 5; ++c)
                gload_lds16(gb + (c << 10) + (lane << 4), wlds + (c << 10));
            if (lane < 16)
                gload_lds4(gb + 5120 + (lane << 2), wlds + 5120);
            asm volatile("s_waitcnt vmcnt(0)" ::: "memory");
            acc += ((volatile float*)wlds)[lane];   // touch LDS, keep DMA live
        }
    }
    sink[(long)blockIdx.x * 256 + t] = acc;
}

// ---------------- k_main: exact R3 (best known) ----------------
__global__ __launch_bounds__(256, 7) void k_main(
    const float* __restrict__ loc_data,
    const float* __restrict__ conf_data,
    const float* __restrict__ occ_data,
    const float* __restrict__ loc_t,
    const int*   __restrict__ conf_t,
    const float* __restrict__ occ_t,
    double* __restrict__ acc,
    int* __restrict__ num_pos,
    float* __restrict__ mine)
{
    __shared__ __align__(16) float tile[4 * RPT * CC];
    __shared__ double red[4][3];

    const int t = threadIdx.x;
    const int w = t >> 6;
    const int lane = t & 63;
    const int r = lane >> 2;
    const int s = lane & 3;
    float* wtile = tile + w * (RPT * CC);
    char* wlds = (char*)wtile;
    const int wave_id = blockIdx.x * 4 + w;
    const int n_waves = NBLK * 4;

    double a_l = 0.0, a_o = 0.0, a_cp = 0.0;

    for (int td = wave_id; td < NT; td += n_waves) {
        const char* gb = (const char*)conf_data + (long)td * TB;
        asm volatile("s_waitcnt lgkmcnt(0)" ::: "memory");
        #pragma unroll
        for (int c = 0; c < 5; ++c)
            gload_lds16(gb + (c << 10) + (lane << 4), wlds + (c << 10));
        if (lane < 16)
            gload_lds4(gb + 5120 + (lane << 2), wlds + 5120);
        asm volatile("s_waitcnt vmcnt(0)" ::: "memory");

        const float* rp = wtile + r * CC;
        const int start = (s == 0) ? 0 : (s * 20 + 1);
        float sum = (s == 0) ? __expf(rp[20]) : 0.0f;
        #pragma unroll
        for (int j = 0; j < 20; ++j) sum += __expf(rp[start + j]);
        sum += __shfl_xor(sum, 1, 64);
        sum += __shfl_xor(sum, 2, 64);

        bool pos = false;
        const long i = (long)td * RPT + r;
        if (s == 0) {
            const int tc = conf_t[i];
            const float cat = rp[tc];
            const float diff = __logf(sum) - cat;
            pos = tc > 0;
            if (pos) {
                a_cp += (double)diff;
                const float4 ld4 = *(const float4*)(loc_data + i * 4);
                const float4 lt4 = *(const float4*)(loc_t + i * 4);
                float sl = 0.0f;
                { float d = ld4.x - lt4.x, ad = fabsf(d); sl += (ad < 1.f) ? 0.5f*d*d : ad - 0.5f; }
                { float d = ld4.y - lt4.y, ad = fabsf(d); sl += (ad < 1.f) ? 0.5f*d*d : ad - 0.5f; }
                { float d = ld4.z - lt4.z, ad = fabsf(d); sl += (ad < 1.f) ? 0.5f*d*d : ad - 0.5f; }
                { float d = ld4.w - lt4.w, ad = fabsf(d); sl += (ad < 1.f) ? 0.5f*d*d : ad - 0.5f; }
                a_l += (double)sl;
                const float ot = occ_t[i];
                if (ot != -1.0f) { const float dd = occ_data[i] - ot; a_o += (double)(dd * dd); }
                mine[i] = 0.0f;
            } else {
                mine[i] = fmaxf(diff, 0.0f);
            }
        }
        const u64 bal = __ballot(pos);
        if (bal != 0ull && lane == 0)
            atomicAdd(&num_pos[td / TPB], (int)__popcll(bal));
    }

    #pragma unroll
    for (int d = 1; d < 64; d <<= 1) {
        a_l  += __shfl_xor(a_l,  d, 64);
        a_o  += __shfl_xor(a_o,  d, 64);
        a_cp += __shfl_xor(a_cp, d, 64);
    }
    if (lane == 0) { red[w][0] = a_l; red[w][1] = a_o; red[w][2] = a_cp; }
    __syncthreads();
    if (t == 0) {
        double x0 = red[0][0] + red[1][0] + red[2][0] + red[3][0];
        double x1 = red[0][1] + red[1][1] + red[2][1] + red[3][1];
        double x2 = red[0][2] + red[1][2] + red[2][2] + red[3][2];
        const int slot = blockIdx.x & (NSLOT - 1);
        atomicAdd(&acc[slot * 3 + 0], x0);
        atomicAdd(&acc[slot * 3 + 1], x1);
        atomicAdd(&acc[slot * 3 + 2], x2);
    }
}

// ---------------- k_select: R3 version, repeated x8 for profiling ----------------
__global__ __launch_bounds__(1024) void k_select(
    const float* __restrict__ mine,
    const int* __restrict__ num_pos,
    double* __restrict__ csel)
{
    __shared__ u32 hist16[16][256];
    __shared__ u32 htot[256];
    __shared__ u32 sh_prefix, sh_kk;
    __shared__ double dred[16];
    __shared__ u32 cred[16];

    const int b = blockIdx.x;
    const int t = threadIdx.x;
    const int w = t >> 6;
    const int lane = t & 63;
    const float* row = mine + (long)b * PP;

    u32 u[25];
    #pragma unroll
    for (int r = 0; r < 25; ++r) {
        const int idx = t + (r << 10);
        u[r] = (idx < PP) ? __float_as_uint(row[idx]) : 0u;
    }

    const int np = num_pos[b];
    int k = NEGPOS * np;
    if (k > PP - 1) k = PP - 1;
    if (k <= 0) return;

    for (int rep = 0; rep < 8; ++rep) {
        u32 prefix = 0, mask = 0, kk = (u32)k;

        for (int pass = 0; pass < 4; ++pass) {
            const int shift = 24 - 8 * pass;
            for (int z = t; z < 16 * 256; z += 1024) ((u32*)hist16)[z] = 0;
            __syncthreads();
            #pragma unroll
            for (int r = 0; r < 25; ++r) {
                const u32 uu = u[r];
                if ((uu & mask) == prefix)
                    atomicAdd(&hist16[w][(uu >> shift) & 255], 1u);
            }
            __syncthreads();
            if (t < 256) {
                u32 s2 = 0;
                #pragma unroll
                for (int j = 0; j < 16; ++j) s2 += hist16[j][t];
                htot[t] = s2;
            }
            __syncthreads();
            if (t < 256) {
                u32 above = 0;
                for (int bb = t + 1; bb < 256; ++bb) above += htot[bb];
                if (above < kk && above + htot[t] >= kk) {
                    sh_prefix = prefix | ((u32)t << shift);
                    sh_kk = kk - above;
                }
            }
            __syncthreads();
            prefix = sh_prefix;
            kk = sh_kk;
            mask |= (0xFFu << shift);
            __syncthreads();
        }

        const u32 thr_bits = prefix;
        const float thr = __uint_as_float(thr_bits);

        double ssum = 0.0;
        u32 cnt = 0;
        #pragma unroll
        for (int r = 0; r < 25; ++r) {
            const u32 uu = u[r];
            if (uu > thr_bits) { ssum += (double)__uint_as_float(uu); cnt++; }
        }
        #pragma unroll
        for (int d = 1; d < 64; d <<= 1) {
            ssum += __shfl_xor(ssum, d, 64);
            cnt  += __shfl_xor(cnt,  d, 64);
        }
        if (lane == 0) { dred[w] = ssum; cred[w] = cnt; }
        __syncthreads();
        if (t == 0 && rep == 0) {
            double S = 0.0; u32 cg = 0;
            #pragma unroll
            for (int j = 0; j < 16; ++j) { S += dred[j]; cg += cred[j]; }
            S += (double)(k - (int)cg) * (double)thr;
            atomicAdd(csel, S);
        }
        __syncthreads();
    }
}

__global__ __launch_bounds__(256) void k_final(
    const double* __restrict__ acc,
    const double* __restrict__ csel,
    const int* __restrict__ num_pos,
    float* __restrict__ out)
{
    __shared__ double red[4][4];
    const int t = threadIdx.x;
    const int w = t >> 6;
    const int lane = t & 63;

    double l = acc[t * 3 + 0];
    double o = acc[t * 3 + 1];
    double c = acc[t * 3 + 2];
    double npd = (t < BB) ? (double)num_pos[t] : 0.0;
    #pragma unroll
    for (int d = 1; d < 64; d <<= 1) {
        l   += __shfl_xor(l,   d, 64);
        o   += __shfl_xor(o,   d, 64);
        c   += __shfl_xor(c,   d, 64);
        npd += __shfl_xor(npd, d, 64);
    }
    if (lane == 0) { red[w][0] = l; red[w][1] = o; red[w][2] = c; red[w][3] = npd; }
    __syncthreads();
    if (t == 0) {
        double L = 0, O = 0, Cp = 0, N = 0;
        #pragma unroll
        for (int j = 0; j < 4; ++j) { L += red[j][0]; O += red[j][1]; Cp += red[j][2]; N += red[j][3]; }
        out[0] = (float)(L / N);
        out[1] = (float)((Cp + csel[0]) / N);
        out[2] = (float)(O / N);
    }
}

extern "C" void kernel_launch(void* const* d_in, const int* in_sizes, int n_in,
                              void* d_out, int out_size, void* d_ws, size_t ws_size,
                              hipStream_t stream) {
    const float* loc_data  = (const float*)d_in[0];
    const float* conf_data = (const float*)d_in[1];
    const float* occ_data  = (const float*)d_in[2];
    const float* loc_t     = (const float*)d_in[3];
    const int*   conf_t    = (const int*)d_in[4];
    const float* occ_t     = (const float*)d_in[5];

    char* ws = (char*)d_ws;
    double* csel   = (double*)ws;
    int*    numpos = (int*)(ws + 64);
    double* acc    = (double*)(ws + 512);
    float*  mine   = (float*)(ws + 8192);

    hipMemsetAsync(ws, 0, 8192, stream);

    // ---- real pipeline first (cold-ish L3, comparable to R3) ----
    k_main<<<NBLK, 256, 0, stream>>>(loc_data, conf_data, occ_data, loc_t,
                                     conf_t, occ_t, acc, numpos, mine);
    k_select<<<BB, 1024, 0, stream>>>(mine, numpos, csel);
    k_final<<<1, 256, 0, stream>>>(acc, csel, numpos, (float*)d_out);

    // ---- diagnostics (sinks live in ws beyond 16 MB) ----
    if (ws_size >= (size_t)(22ull << 20)) {
        float* sink1 = (float*)(ws + (16ull << 20));   // 2 MB
        float* sink3 = (float*)(ws + (20ull << 20));   // 1.75 MB
        k_probe_read<<<2048, 256, 0, stream>>>((const float4*)conf_data, N4C, 4, sink1);
        k_probe_lds<<<NBLK, 256, 0, stream>>>(conf_data, 4, sink3);

        if (ws_size >= (size_t)(96ull << 20)) {
            float* sink2 = (float*)(ws + (18ull << 20));
            const long win = (long)((ws_size - (32ull << 20) > (512ull << 20))
                                    ? (512ull << 20) : (ws_size - (32ull << 20)));
            const long n4_2 = win / 16;
            k_probe_read<<<2048, 256, 0, stream>>>(
                (const float4*)(ws + (32ull << 20)), n4_2, 2, sink2);
        }
    }
}

// Round 8
// 296.335 us; speedup vs baseline: 4.4795x; 4.4795x over previous
//
#include <hip/hip_runtime.h>
#include <stdint.h>

#define BB 64
#define PP 24656
#define CC 81
#define NEGPOS 3
#define RPT 16                     // rows per wave-tile
#define NT ((BB * PP) / RPT)       // 98624 tiles
#define TPB (PP / RPT)             // 1541 tiles per batch row
#define ROWS (BB * PP)
#define NSLOT 256
#define NBLK 2048

typedef unsigned int u32;
typedef unsigned long long u64;

// ws layout:
//   [0]      double csel
//   [64]     int num_pos[64]
//   [512]    double acc[NSLOT*3]   (l, o, cp)
//   [8192]   float mine[ROWS]

// chunk processing: elements x = c*256 + 4*lane + {0..3}, exp'd, split by row
// (row = x/81 via magic mul), pair-combined, atomically added to slots.
#define CHUNK(c, b) do { \
    const int x = (c) * 256 + (lane << 2); \
    const int r = (x * 12946) >> 20;          /* x/81 exact for x<1296 */ \
    const int rem = x - r * 81; \
    const float e0 = __expf((b).x), e1 = __expf((b).y); \
    const float e2 = __expf((b).z), e3 = __expf((b).w); \
    float lo = e0, hi = 0.0f; \
    if (rem < 80) lo += e1; else hi += e1; \
    if (rem < 79) lo += e2; else hi += e2; \
    if (rem < 78) lo += e3; else hi += e3; \
    const float plo = __shfl_xor(lo, 1, 64); \
    const int   pr  = __shfl_xor(r, 1, 64); \
    const bool send = ((lane & 1) == 1) && (pr == r); \
    if (((lane & 1) == 0) && (pr == r)) lo += plo; \
    if (!send) atomicAdd(&st[r], lo); \
    if (rem >= 78) atomicAdd(&st[r + 1], hi); \
} while (0)

__global__ __launch_bounds__(256) void k_main(
    const float* __restrict__ conf_data,
    const int*   __restrict__ conf_t,
    float* __restrict__ mine,
    double* __restrict__ acc,     // NSLOT*3
    int* __restrict__ num_pos)    // 64
{
    __shared__ float slots[4][16];
    __shared__ double red[4];

    const int t = threadIdx.x;
    const int w = t >> 6;
    const int lane = t & 63;
    float* st = slots[w];
    const int wid = blockIdx.x * 4 + w;
    const int nw = NBLK * 4;

    double a_cp = 0.0;

    // prologue: tc for first tile
    int tc_cur = 0;
    if (wid < NT && lane < 16) tc_cur = conf_t[(long)wid * RPT + lane];

    for (int td = wid; td < NT; td += nw) {
        const long rowbase = (long)td * RPT;

        // --- issue ALL VMEM up front, no dependent loads in compute ---
        float catv = 0.0f;
        if (lane < 16)
            catv = conf_data[(rowbase + lane) * CC + tc_cur];   // addr from prefetched tc

        const float4* g4 = (const float4*)(conf_data + rowbase * CC);
        const float4 b0 = g4[lane];
        const float4 b1 = g4[64 + lane];
        const float4 b2 = g4[128 + lane];
        const float4 b3 = g4[192 + lane];
        const float4 b4 = g4[256 + lane];
        float4 bt = make_float4(0.f, 0.f, 0.f, 0.f);
        if (lane < 4) bt = g4[320 + lane];

        int tc_nxt = 0;
        const int tdn = td + nw;
        if (tdn < NT && lane < 16) tc_nxt = conf_t[(long)tdn * RPT + lane];

        // --- wave-private slot accumulate (DS in-order per wave, no barrier) ---
        if (lane < 16) st[lane] = 0.0f;

        CHUNK(0, b0);
        CHUNK(1, b1);
        CHUNK(2, b2);
        CHUNK(3, b3);
        CHUNK(4, b4);
        if (lane < 4) {   // elements 1280..1295, all row 15
            const float s = __expf(bt.x) + __expf(bt.y) + __expf(bt.z) + __expf(bt.w);
            atomicAdd(&st[15], s);
        }

        // --- finish rows ---
        bool pos = false;
        if (lane < 16) {
            const float sum = st[lane];
            const float diff = __logf(sum) - catv;
            pos = tc_cur > 0;
            a_cp += pos ? (double)diff : 0.0;
            mine[rowbase + lane] = pos ? 0.0f : fmaxf(diff, 0.0f);
        }
        const u64 bal = __ballot(pos);
        if (bal != 0ull && lane == 0)
            atomicAdd(&num_pos[td / TPB], (int)__popcll(bal));

        tc_cur = tc_nxt;
    }

    #pragma unroll
    for (int d = 1; d < 64; d <<= 1) a_cp += __shfl_xor(a_cp, d, 64);
    if (lane == 0) red[w] = a_cp;
    __syncthreads();
    if (t == 0) {
        const double x = red[0] + red[1] + red[2] + red[3];
        atomicAdd(&acc[(blockIdx.x & (NSLOT - 1)) * 3 + 2], x);
    }
}

// ---------------- k_pos: loc smooth-L1 + occlusion MSE for positive rows ----
__global__ __launch_bounds__(256) void k_pos(
    const float* __restrict__ loc_data,
    const float* __restrict__ occ_data,
    const float* __restrict__ loc_t,
    const int*   __restrict__ conf_t,
    const float* __restrict__ occ_t,
    double* __restrict__ acc)     // NSLOT*3
{
    __shared__ double red[4][2];
    const int t = threadIdx.x;
    const int w = t >> 6;
    const int lane = t & 63;
    const int tid = blockIdx.x * 256 + t;
    const int nthr = gridDim.x * 256;
    const int nchunk = ROWS / 4;

    double a_l = 0.0, a_o = 0.0;

    for (int c = tid; c < nchunk; c += nthr) {
        const int4 tc4 = ((const int4*)conf_t)[c];
        #pragma unroll
        for (int e = 0; e < 4; ++e) {
            const int tc = (e == 0) ? tc4.x : (e == 1) ? tc4.y : (e == 2) ? tc4.z : tc4.w;
            if (tc > 0) {
                const long i = (long)c * 4 + e;
                const float4 ld4 = *(const float4*)(loc_data + i * 4);
                const float4 lt4 = *(const float4*)(loc_t + i * 4);
                float sl = 0.0f;
                { float d = ld4.x - lt4.x, ad = fabsf(d); sl += (ad < 1.f) ? 0.5f*d*d : ad - 0.5f; }
                { float d = ld4.y - lt4.y, ad = fabsf(d); sl += (ad < 1.f) ? 0.5f*d*d : ad - 0.5f; }
                { float d = ld4.z - lt4.z, ad = fabsf(d); sl += (ad < 1.f) ? 0.5f*d*d : ad - 0.5f; }
                { float d = ld4.w - lt4.w, ad = fabsf(d); sl += (ad < 1.f) ? 0.5f*d*d : ad - 0.5f; }
                a_l += (double)sl;
                const float ot = occ_t[i];
                if (ot != -1.0f) { const float dd = occ_data[i] - ot; a_o += (double)(dd * dd); }
            }
        }
    }

    #pragma unroll
    for (int d = 1; d < 64; d <<= 1) {
        a_l += __shfl_xor(a_l, d, 64);
        a_o += __shfl_xor(a_o, d, 64);
    }
    if (lane == 0) { red[w][0] = a_l; red[w][1] = a_o; }
    __syncthreads();
    if (t == 0) {
        const double x0 = red[0][0] + red[1][0] + red[2][0] + red[3][0];
        const double x1 = red[0][1] + red[1][1] + red[2][1] + red[3][1];
        const int slot = blockIdx.x & (NSLOT - 1);
        atomicAdd(&acc[slot * 3 + 0], x0);
        atomicAdd(&acc[slot * 3 + 1], x1);
    }
}

// ---------------- k_select: radix k-th largest, ballot-match histogram ----
__global__ __launch_bounds__(1024) void k_select(
    const float* __restrict__ mine,
    const int* __restrict__ num_pos,
    double* __restrict__ csel)
{
    __shared__ u32 hist[256];
    __shared__ u32 sh_prefix, sh_kk;
    __shared__ double dred[16];
    __shared__ u32 cred[16];

    const int b = blockIdx.x;
    const int t = threadIdx.x;
    const int w = t >> 6;
    const int lane = t & 63;
    const float* row = mine + (long)b * PP;

    u32 u[25];
    #pragma unroll
    for (int r = 0; r < 25; ++r) {
        const int idx = t + (r << 10);
        u[r] = (idx < PP) ? __float_as_uint(row[idx]) : 0u;  // +0.0 pads sort last
    }

    const int np = num_pos[b];
    int k = NEGPOS * np;
    if (k > PP - 1) k = PP - 1;
    if (k <= 0) return;   // uniform across block

    u32 prefix = 0, mask = 0, kk = (u32)k;

    for (int pass = 0; pass < 4; ++pass) {
        const int shift = 24 - 8 * pass;
        if (t < 256) hist[t] = 0;
        __syncthreads();
        #pragma unroll
        for (int r = 0; r < 25; ++r) {
            const u32 uu = u[r];
            const bool valid = (uu & mask) == prefix;
            const u32 bin = (uu >> shift) & 255u;
            u64 eq = __ballot(valid);
            #pragma unroll
            for (int bi = 0; bi < 8; ++bi) {
                const u64 bal = __ballot((bin >> bi) & 1u);
                eq &= ((bin >> bi) & 1u) ? bal : ~bal;
            }
            if (valid && ((int)__ffsll(eq) - 1 == lane))
                atomicAdd(&hist[bin], (u32)__popcll(eq));
        }
        __syncthreads();
        if (t < 256) {
            u32 above = 0;
            for (int bb = t + 1; bb < 256; ++bb) above += hist[bb];
            if (above < kk && above + hist[t] >= kk) {   // exactly one bin
                sh_prefix = prefix | ((u32)t << shift);
                sh_kk = kk - above;
            }
        }
        __syncthreads();
        prefix = sh_prefix;
        kk = sh_kk;
        mask |= (0xFFu << shift);
        __syncthreads();
    }

    const u32 thr_bits = prefix;
    const float thr = __uint_as_float(thr_bits);

    double ssum = 0.0;
    u32 cnt = 0;
    #pragma unroll
    for (int r = 0; r < 25; ++r) {
        const u32 uu = u[r];
        if (uu > thr_bits) { ssum += (double)__uint_as_float(uu); cnt++; }
    }
    #pragma unroll
    for (int d = 1; d < 64; d <<= 1) {
        ssum += __shfl_xor(ssum, d, 64);
        cnt  += __shfl_xor(cnt,  d, 64);
    }
    if (lane == 0) { dred[w] = ssum; cred[w] = cnt; }
    __syncthreads();
    if (t == 0) {
        double S = 0.0; u32 cg = 0;
        #pragma unroll
        for (int j = 0; j < 16; ++j) { S += dred[j]; cg += cred[j]; }
        S += (double)(k - (int)cg) * (double)thr;   // ties at threshold value
        atomicAdd(csel, S);
    }
}

__global__ __launch_bounds__(256) void k_final(
    const double* __restrict__ acc,
    const double* __restrict__ csel,
    const int* __restrict__ num_pos,
    float* __restrict__ out)
{
    __shared__ double red[4][4];
    const int t = threadIdx.x;
    const int w = t >> 6;
    const int lane = t & 63;

    double l = acc[t * 3 + 0];
    double o = acc[t * 3 + 1];
    double c = acc[t * 3 + 2];
    double npd = (t < BB) ? (double)num_pos[t] : 0.0;
    #pragma unroll
    for (int d = 1; d < 64; d <<= 1) {
        l   += __shfl_xor(l,   d, 64);
        o   += __shfl_xor(o,   d, 64);
        c   += __shfl_xor(c,   d, 64);
        npd += __shfl_xor(npd, d, 64);
    }
    if (lane == 0) { red[w][0] = l; red[w][1] = o; red[w][2] = c; red[w][3] = npd; }
    __syncthreads();
    if (t == 0) {
        double L = 0, O = 0, Cp = 0, N = 0;
        #pragma unroll
        for (int j = 0; j < 4; ++j) { L += red[j][0]; O += red[j][1]; Cp += red[j][2]; N += red[j][3]; }
        out[0] = (float)(L / N);
        out[1] = (float)((Cp + csel[0]) / N);
        out[2] = (float)(O / N);
    }
}

extern "C" void kernel_launch(void* const* d_in, const int* in_sizes, int n_in,
                              void* d_out, int out_size, void* d_ws, size_t ws_size,
                              hipStream_t stream) {
    const float* loc_data  = (const float*)d_in[0];
    const float* conf_data = (const float*)d_in[1];
    const float* occ_data  = (const float*)d_in[2];
    const float* loc_t     = (const float*)d_in[3];
    const int*   conf_t    = (const int*)d_in[4];
    const float* occ_t     = (const float*)d_in[5];

    char* ws = (char*)d_ws;
    double* csel   = (double*)ws;            // 1 double
    int*    numpos = (int*)(ws + 64);        // 64 ints
    double* acc    = (double*)(ws + 512);    // NSLOT*3 doubles
    float*  mine   = (float*)(ws + 8192);    // ROWS floats

    hipMemsetAsync(ws, 0, 8192, stream);

    k_main<<<NBLK, 256, 0, stream>>>(conf_data, conf_t, mine, acc, numpos);
    k_pos<<<512, 256, 0, stream>>>(loc_data, occ_data, loc_t, conf_t, occ_t, acc);
    k_select<<<BB, 1024, 0, stream>>>(mine, numpos, csel);
    k_final<<<1, 256, 0, stream>>>(acc, csel, numpos, (float*)d_out);
}

// Round 9
// 288.260 us; speedup vs baseline: 4.6050x; 1.0280x over previous
//
#include <hip/hip_runtime.h>
#include <stdint.h>

#define BB 64
#define PP 24656
#define CC 81
#define NEGPOS 3
#define RPT 16                     // rows per wave tile
#define TB (RPT * CC * 4)          // 5184 B = 5*1024 + 64
#define TFLT (RPT * CC)            // 1296 floats
#define NT ((BB * PP) / RPT)       // 98624 tiles
#define TPB (PP / RPT)             // 1541 tiles per batch row
#define ROWS (BB * PP)
#define NSLOT 256
#define NBLK 768                   // 3 blocks/CU (LDS-bound: 41.5 KB/block)

typedef unsigned int u32;
typedef unsigned long long u64;

// ws layout:
//   [0]      double csel
//   [64]     int num_pos[64]
//   [512]    double acc[NSLOT*3]   (l, o, cp)
//   [8192]   float mine[ROWS]

__device__ __forceinline__ void gload_lds16(const void* g, void* l) {
    __builtin_amdgcn_global_load_lds(
        (const __attribute__((address_space(1))) u32*)g,
        (__attribute__((address_space(3))) u32*)l, 16, 0, 0);
}
__device__ __forceinline__ void gload_lds4(const void* g, void* l) {
    __builtin_amdgcn_global_load_lds(
        (const __attribute__((address_space(1))) u32*)g,
        (__attribute__((address_space(3))) u32*)l, 4, 0, 0);
}

__global__ __launch_bounds__(256, 3) void k_main(
    const float* __restrict__ conf_data,
    const int*   __restrict__ conf_t,
    float* __restrict__ mine,
    double* __restrict__ acc,     // NSLOT*3
    int* __restrict__ num_pos)    // 64
{
    // per-wave double-buffered tile
    __shared__ __align__(16) float tile[4][2][TFLT];   // 41472 B
    __shared__ double red[4];

    const int t = threadIdx.x;
    const int w = t >> 6;
    const int lane = t & 63;
    const int r = lane >> 2;        // row within tile
    const int s = lane & 3;         // quarter-row segment
    const int wid = blockIdx.x * 4 + w;
    const int nw = NBLK * 4;        // 3072 waves

    double a_cp = 0.0;

    // ---- prologue: stage tile(wid) into buf0, prefetch its tc ----
    int tc_cur = 0;
    {
        const char* gb = (const char*)conf_data + (long)wid * TB;
        char* wl = (char*)tile[w][0];
        #pragma unroll
        for (int c = 0; c < 5; ++c)
            gload_lds16(gb + (c << 10) + (lane << 4), wl + (c << 10));
        if (lane < 16) {
            gload_lds4(gb + 5120 + (lane << 2), wl + 5120);
            tc_cur = conf_t[(long)wid * RPT + lane];   // lane l holds tc of row l
        }
    }

    int cur = 0;
    for (int td = wid; td < NT; td += nw) {
        const int tdn = td + nw;
        int tc_nxt = 0;
        if (tdn < NT) {
            // prefetch next tile (6 loads + 1 tc) into other buffer
            const char* gb = (const char*)conf_data + (long)tdn * TB;
            char* wl = (char*)tile[w][cur ^ 1];
            asm volatile("s_waitcnt lgkmcnt(0)" ::: "memory");  // prior ds_reads retired
            #pragma unroll
            for (int c = 0; c < 5; ++c)
                gload_lds16(gb + (c << 10) + (lane << 4), wl + (c << 10));
            if (lane < 16) {
                gload_lds4(gb + 5120 + (lane << 2), wl + 5120);
                tc_nxt = conf_t[(long)tdn * RPT + lane];
            }
            // retire current tile's 6 loads (+its tc), keep the 7 prefetch ops in flight
            asm volatile("s_waitcnt vmcnt(8)" ::: "memory");
        } else {
            asm volatile("s_waitcnt vmcnt(0)" ::: "memory");
        }

        // ---- compute from LDS buf(cur): no VMEM reads in this phase ----
        const float* rp = tile[w][cur] + r * CC;
        const int start = (s == 0) ? 0 : (s * 20 + 1);   // 21|20|20|20 split
        float sum = (s == 0) ? __expf(rp[20]) : 0.0f;
        #pragma unroll
        for (int j = 0; j < 20; ++j) sum += __expf(rp[start + j]);
        sum += __shfl_xor(sum, 1, 64);
        sum += __shfl_xor(sum, 2, 64);   // 4 lanes of a row now hold the row sum

        const int tc_v = __shfl(tc_cur, r, 64);   // row r's target class (from lane r)
        bool pos = false;
        if (s == 0) {
            const float cat = rp[tc_v];           // LDS gather
            const float diff = __logf(sum) - cat; // lse - conf_at_t
            pos = tc_v > 0;
            a_cp += pos ? (double)diff : 0.0;
            mine[(long)td * RPT + r] = pos ? 0.0f : fmaxf(diff, 0.0f);
        }
        const u64 bal = __ballot(pos);
        if (bal != 0ull && lane == 0)
            atomicAdd(&num_pos[td / TPB], (int)__popcll(bal));

        tc_cur = tc_nxt;
        cur ^= 1;
    }

    #pragma unroll
    for (int d = 1; d < 64; d <<= 1) a_cp += __shfl_xor(a_cp, d, 64);
    if (lane == 0) red[w] = a_cp;
    __syncthreads();
    if (t == 0) {
        const double x = red[0] + red[1] + red[2] + red[3];
        atomicAdd(&acc[(blockIdx.x & (NSLOT - 1)) * 3 + 2], x);
    }
}

// ---------------- k_pos: loc smooth-L1 + occlusion MSE for positive rows ----
__global__ __launch_bounds__(256) void k_pos(
    const float* __restrict__ loc_data,
    const float* __restrict__ occ_data,
    const float* __restrict__ loc_t,
    const int*   __restrict__ conf_t,
    const float* __restrict__ occ_t,
    double* __restrict__ acc)     // NSLOT*3
{
    __shared__ double red[4][2];
    const int t = threadIdx.x;
    const int w = t >> 6;
    const int lane = t & 63;
    const int tid = blockIdx.x * 256 + t;
    const int nthr = gridDim.x * 256;
    const int nchunk = ROWS / 4;

    double a_l = 0.0, a_o = 0.0;

    for (int c = tid; c < nchunk; c += nthr) {
        const int4 tc4 = ((const int4*)conf_t)[c];
        #pragma unroll
        for (int e = 0; e < 4; ++e) {
            const int tc = (e == 0) ? tc4.x : (e == 1) ? tc4.y : (e == 2) ? tc4.z : tc4.w;
            if (tc > 0) {
                const long i = (long)c * 4 + e;
                const float4 ld4 = *(const float4*)(loc_data + i * 4);
                const float4 lt4 = *(const float4*)(loc_t + i * 4);
                float sl = 0.0f;
                { float d = ld4.x - lt4.x, ad = fabsf(d); sl += (ad < 1.f) ? 0.5f*d*d : ad - 0.5f; }
                { float d = ld4.y - lt4.y, ad = fabsf(d); sl += (ad < 1.f) ? 0.5f*d*d : ad - 0.5f; }
                { float d = ld4.z - lt4.z, ad = fabsf(d); sl += (ad < 1.f) ? 0.5f*d*d : ad - 0.5f; }
                { float d = ld4.w - lt4.w, ad = fabsf(d); sl += (ad < 1.f) ? 0.5f*d*d : ad - 0.5f; }
                a_l += (double)sl;
                const float ot = occ_t[i];
                if (ot != -1.0f) { const float dd = occ_data[i] - ot; a_o += (double)(dd * dd); }
            }
        }
    }

    #pragma unroll
    for (int d = 1; d < 64; d <<= 1) {
        a_l += __shfl_xor(a_l, d, 64);
        a_o += __shfl_xor(a_o, d, 64);
    }
    if (lane == 0) { red[w][0] = a_l; red[w][1] = a_o; }
    __syncthreads();
    if (t == 0) {
        const double x0 = red[0][0] + red[1][0] + red[2][0] + red[3][0];
        const double x1 = red[0][1] + red[1][1] + red[2][1] + red[3][1];
        const int slot = blockIdx.x & (NSLOT - 1);
        atomicAdd(&acc[slot * 3 + 0], x0);
        atomicAdd(&acc[slot * 3 + 1], x1);
    }
}

// ---------------- k_select: radix k-th largest, ballot-match histogram ----
__global__ __launch_bounds__(1024) void k_select(
    const float* __restrict__ mine,
    const int* __restrict__ num_pos,
    double* __restrict__ csel)
{
    __shared__ u32 hist[256];
    __shared__ u32 sh_prefix, sh_kk;
    __shared__ double dred[16];
    __shared__ u32 cred[16];

    const int b = blockIdx.x;
    const int t = threadIdx.x;
    const int w = t >> 6;
    const int lane = t & 63;
    const float* row = mine + (long)b * PP;

    u32 u[25];
    #pragma unroll
    for (int r = 0; r < 25; ++r) {
        const int idx = t + (r << 10);
        u[r] = (idx < PP) ? __float_as_uint(row[idx]) : 0u;  // +0.0 pads sort last
    }

    const int np = num_pos[b];
    int k = NEGPOS * np;
    if (k > PP - 1) k = PP - 1;
    if (k <= 0) return;   // uniform across block

    u32 prefix = 0, mask = 0, kk = (u32)k;

    for (int pass = 0; pass < 4; ++pass) {
        const int shift = 24 - 8 * pass;
        if (t < 256) hist[t] = 0;
        __syncthreads();
        #pragma unroll
        for (int r = 0; r < 25; ++r) {
            const u32 uu = u[r];
            const bool valid = (uu & mask) == prefix;
            const u32 bin = (uu >> shift) & 255u;
            u64 eq = __ballot(valid);
            #pragma unroll
            for (int bi = 0; bi < 8; ++bi) {
                const u64 bal = __ballot((bin >> bi) & 1u);
                eq &= ((bin >> bi) & 1u) ? bal : ~bal;
            }
            if (valid && ((int)__ffsll(eq) - 1 == lane))
                atomicAdd(&hist[bin], (u32)__popcll(eq));
        }
        __syncthreads();
        if (t < 256) {
            u32 above = 0;
            for (int bb = t + 1; bb < 256; ++bb) above += hist[bb];
            if (above < kk && above + hist[t] >= kk) {   // exactly one bin
                sh_prefix = prefix | ((u32)t << shift);
                sh_kk = kk - above;
            }
        }
        __syncthreads();
        prefix = sh_prefix;
        kk = sh_kk;
        mask |= (0xFFu << shift);
        __syncthreads();
    }

    const u32 thr_bits = prefix;
    const float thr = __uint_as_float(thr_bits);

    double ssum = 0.0;
    u32 cnt = 0;
    #pragma unroll
    for (int r = 0; r < 25; ++r) {
        const u32 uu = u[r];
        if (uu > thr_bits) { ssum += (double)__uint_as_float(uu); cnt++; }
    }
    #pragma unroll
    for (int d = 1; d < 64; d <<= 1) {
        ssum += __shfl_xor(ssum, d, 64);
        cnt  += __shfl_xor(cnt,  d, 64);
    }
    if (lane == 0) { dred[w] = ssum; cred[w] = cnt; }
    __syncthreads();
    if (t == 0) {
        double S = 0.0; u32 cg = 0;
        #pragma unroll
        for (int j = 0; j < 16; ++j) { S += dred[j]; cg += cred[j]; }
        S += (double)(k - (int)cg) * (double)thr;   // ties at threshold value
        atomicAdd(csel, S);
    }
}

__global__ __launch_bounds__(256) void k_final(
    const double* __restrict__ acc,
    const double* __restrict__ csel,
    const int* __restrict__ num_pos,
    float* __restrict__ out)
{
    __shared__ double red[4][4];
    const int t = threadIdx.x;
    const int w = t >> 6;
    const int lane = t & 63;

    double l = acc[t * 3 + 0];
    double o = acc[t * 3 + 1];
    double c = acc[t * 3 + 2];
    double npd = (t < BB) ? (double)num_pos[t] : 0.0;
    #pragma unroll
    for (int d = 1; d < 64; d <<= 1) {
        l   += __shfl_xor(l,   d, 64);
        o   += __shfl_xor(o,   d, 64);
        c   += __shfl_xor(c,   d, 64);
        npd += __shfl_xor(npd, d, 64);
    }
    if (lane == 0) { red[w][0] = l; red[w][1] = o; red[w][2] = c; red[w][3] = npd; }
    __syncthreads();
    if (t == 0) {
        double L = 0, O = 0, Cp = 0, N = 0;
        #pragma unroll
        for (int j = 0; j < 4; ++j) { L += red[j][0]; O += red[j][1]; Cp += red[j][2]; N += red[j][3]; }
        out[0] = (float)(L / N);
        out[1] = (float)((Cp + csel[0]) / N);
        out[2] = (float)(O / N);
    }
}

extern "C" void kernel_launch(void* const* d_in, const int* in_sizes, int n_in,
                              void* d_out, int out_size, void* d_ws, size_t ws_size,
                              hipStream_t stream) {
    const float* loc_data  = (const float*)d_in[0];
    const float* conf_data = (const float*)d_in[1];
    const float* occ_data  = (const float*)d_in[2];
    const float* loc_t     = (const float*)d_in[3];
    const int*   conf_t    = (const int*)d_in[4];
    const float* occ_t     = (const float*)d_in[5];

    char* ws = (char*)d_ws;
    double* csel   = (double*)ws;            // 1 double
    int*    numpos = (int*)(ws + 64);        // 64 ints
    double* acc    = (double*)(ws + 512);    // NSLOT*3 doubles
    float*  mine   = (float*)(ws + 8192);    // ROWS floats

    hipMemsetAsync(ws, 0, 8192, stream);

    k_main<<<NBLK, 256, 0, stream>>>(conf_data, conf_t, mine, acc, numpos);
    k_pos<<<512, 256, 0, stream>>>(loc_data, occ_data, loc_t, conf_t, occ_t, acc);
    k_select<<<BB, 1024, 0, stream>>>(mine, numpos, csel);
    k_final<<<1, 256, 0, stream>>>(acc, csel, numpos, (float*)d_out);
}

// Round 10
// 188.021 us; speedup vs baseline: 7.0600x; 1.5331x over previous
//
#include <hip/hip_runtime.h>
#include <stdint.h>

#define BB 64
#define PP 24656
#define CC 81
#define NEGPOS 3
#define RPT 16                     // rows per wave tile
#define TB (RPT * CC * 4)          // 5184 B = 5*1024 + 64
#define TFLT (RPT * CC)            // 1296 floats
#define NT ((BB * PP) / RPT)       // 98624 tiles
#define ROWS (BB * PP)
#define NBLK 1792                  // 7 blocks/CU -> 28 waves/CU

typedef unsigned int u32;
typedef unsigned long long u64;

// ws layout:
//   [0]      int num_pos[64]
//   [256]    double blk[64][4]   (l, o, cp, sel) per batch row
//   [4096]   float mine[ROWS]

__device__ __forceinline__ void gload_lds16(const void* g, void* l) {
    __builtin_amdgcn_global_load_lds(
        (const __attribute__((address_space(1))) u32*)g,
        (__attribute__((address_space(3))) u32*)l, 16, 0, 0);
}
__device__ __forceinline__ void gload_lds4(const void* g, void* l) {
    __builtin_amdgcn_global_load_lds(
        (const __attribute__((address_space(1))) u32*)g,
        (__attribute__((address_space(3))) u32*)l, 4, 0, 0);
}

// ---------------- k_main: pure lse/diff stream. Compute phase has ZERO VMEM:
// next tile's conf rows AND conf_t are issued before the drain. ----------------
__global__ __launch_bounds__(256, 7) void k_main(
    const float* __restrict__ conf_data,
    const int*   __restrict__ conf_t,
    float* __restrict__ mine)
{
    __shared__ __align__(16) float tile[4][TFLT];   // 20736 B -> 7 blocks/CU
    const int t = threadIdx.x;
    const int w = t >> 6;
    const int lane = t & 63;
    const int r = lane >> 2;        // row within tile
    const int s = lane & 3;         // quarter-row segment
    float* wt = tile[w];
    char* wl = (char*)wt;
    const int wid = blockIdx.x * 4 + w;
    const int nw = NBLK * 4;        // 7168 waves

    // prologue: stage tile(wid) + its tc
    int tc_cur = 0;
    {
        const char* gb = (const char*)conf_data + (long)wid * TB;
        #pragma unroll
        for (int c = 0; c < 5; ++c)
            gload_lds16(gb + (c << 10) + (lane << 4), wl + (c << 10));
        if (lane < 16) {
            gload_lds4(gb + 5120 + (lane << 2), wl + 5120);
            tc_cur = conf_t[(long)wid * RPT + lane];
        }
    }

    for (int td = wid; td < NT; td += nw) {
        asm volatile("s_waitcnt vmcnt(0)" ::: "memory");   // tile + tc resident

        // ---- compute from LDS: no VMEM reads ----
        const float* rp = wt + r * CC;
        const int start = (s == 0) ? 0 : (s * 20 + 1);     // 21|20|20|20 split
        float sum = (s == 0) ? __expf(rp[20]) : 0.0f;
        #pragma unroll
        for (int j = 0; j < 20; ++j) sum += __expf(rp[start + j]);
        sum += __shfl_xor(sum, 1, 64);
        sum += __shfl_xor(sum, 2, 64);     // 4 lanes of a row hold the row sum

        const int tc_v = __shfl(tc_cur, r, 64);   // row r's target class
        if (s == 0) {
            const float cat = rp[tc_v];
            mine[(long)td * RPT + r] = fmaxf(__logf(sum) - cat, 0.0f);
        }

        // ---- issue next tile (6 DMA + tc), then loop back to drain ----
        const int tdn = td + nw;
        if (tdn < NT) {
            asm volatile("s_waitcnt lgkmcnt(0)" ::: "memory");  // ds_reads retired
            const char* gb = (const char*)conf_data + (long)tdn * TB;
            #pragma unroll
            for (int c = 0; c < 5; ++c)
                gload_lds16(gb + (c << 10) + (lane << 4), wl + (c << 10));
            if (lane < 16) {
                gload_lds4(gb + 5120 + (lane << 2), wl + 5120);
                tc_cur = conf_t[(long)tdn * RPT + lane];
            }
        }
    }
}

// ---------------- k_select: per batch row — pos mask, np, a_cp/a_l/a_o,
// then radix k-th largest via ballot-match histogram. One kernel does it all.
__global__ __launch_bounds__(1024) void k_select(
    const float* __restrict__ mine,
    const int*   __restrict__ conf_t,
    const float* __restrict__ loc_data,
    const float* __restrict__ loc_t,
    const float* __restrict__ occ_data,
    const float* __restrict__ occ_t,
    double* __restrict__ blk,     // [BB][4]
    int* __restrict__ num_pos)    // [BB]
{
    __shared__ u32 hist[256];
    __shared__ u32 sh_prefix, sh_kk;
    __shared__ double dred[16][3];
    __shared__ int ired[16];
    __shared__ double dsum[16];
    __shared__ u32 cred[16];

    const int b = blockIdx.x;
    const int t = threadIdx.x;
    const int w = t >> 6;
    const int lane = t & 63;
    const long base = (long)b * PP;
    const float* row = mine + base;
    const int* tcr = conf_t + base;

    u32 u[25];
    int np_t = 0;
    double a_l = 0.0, a_o = 0.0, a_cp = 0.0;

    #pragma unroll
    for (int r2 = 0; r2 < 25; ++r2) {
        const int idx = t + (r2 << 10);
        u32 uu = 0u;
        if (idx < PP) {
            uu = __float_as_uint(row[idx]);
            const int tc = tcr[idx];
            if (tc > 0) {
                ++np_t;
                a_cp += (double)__uint_as_float(uu);
                const long i = base + idx;
                const float4 ld4 = *(const float4*)(loc_data + i * 4);
                const float4 lt4 = *(const float4*)(loc_t + i * 4);
                float sl = 0.0f;
                { float d = ld4.x - lt4.x, ad = fabsf(d); sl += (ad < 1.f) ? 0.5f*d*d : ad - 0.5f; }
                { float d = ld4.y - lt4.y, ad = fabsf(d); sl += (ad < 1.f) ? 0.5f*d*d : ad - 0.5f; }
                { float d = ld4.z - lt4.z, ad = fabsf(d); sl += (ad < 1.f) ? 0.5f*d*d : ad - 0.5f; }
                { float d = ld4.w - lt4.w, ad = fabsf(d); sl += (ad < 1.f) ? 0.5f*d*d : ad - 0.5f; }
                a_l += (double)sl;
                const float ot = occ_t[i];
                if (ot != -1.0f) { const float dd = occ_data[i] - ot; a_o += (double)(dd * dd); }
                uu = 0u;                       // exclude pos from mining
            }
        }
        u[r2] = uu;
    }

    // block-reduce np and the three loss partials
    #pragma unroll
    for (int d = 1; d < 64; d <<= 1) {
        a_l  += __shfl_xor(a_l,  d, 64);
        a_o  += __shfl_xor(a_o,  d, 64);
        a_cp += __shfl_xor(a_cp, d, 64);
        np_t += __shfl_xor(np_t, d, 64);
    }
    if (lane == 0) { dred[w][0] = a_l; dred[w][1] = a_o; dred[w][2] = a_cp; ired[w] = np_t; }
    __syncthreads();
    int np = 0;
    #pragma unroll
    for (int j = 0; j < 16; ++j) np += ired[j];
    if (t == 0) {
        double L = 0, O = 0, Cp = 0;
        #pragma unroll
        for (int j = 0; j < 16; ++j) { L += dred[j][0]; O += dred[j][1]; Cp += dred[j][2]; }
        blk[b * 4 + 0] = L;
        blk[b * 4 + 1] = O;
        blk[b * 4 + 2] = Cp;
        num_pos[b] = np;
    }

    int k = NEGPOS * np;
    if (k > PP - 1) k = PP - 1;
    if (k <= 0) {                    // uniform across block
        if (t == 0) blk[b * 4 + 3] = 0.0;
        return;
    }

    u32 prefix = 0, mask = 0, kk = (u32)k;

    for (int pass = 0; pass < 4; ++pass) {
        const int shift = 24 - 8 * pass;
        if (t < 256) hist[t] = 0;
        __syncthreads();
        #pragma unroll
        for (int r2 = 0; r2 < 25; ++r2) {
            const u32 uu = u[r2];
            const bool valid = (uu & mask) == prefix;
            const u32 bin = (uu >> shift) & 255u;
            u64 eq = __ballot(valid);
            #pragma unroll
            for (int bi = 0; bi < 8; ++bi) {
                const u64 bal = __ballot((bin >> bi) & 1u);
                eq &= ((bin >> bi) & 1u) ? bal : ~bal;
            }
            if (valid && ((int)__ffsll(eq) - 1 == lane))
                atomicAdd(&hist[bin], (u32)__popcll(eq));
        }
        __syncthreads();
        if (t < 256) {
            u32 above = 0;
            for (int bb = t + 1; bb < 256; ++bb) above += hist[bb];
            if (above < kk && above + hist[t] >= kk) {   // exactly one bin
                sh_prefix = prefix | ((u32)t << shift);
                sh_kk = kk - above;
            }
        }
        __syncthreads();
        prefix = sh_prefix;
        kk = sh_kk;
        mask |= (0xFFu << shift);
        __syncthreads();
    }

    const u32 thr_bits = prefix;
    const float thr = __uint_as_float(thr_bits);

    double ssum = 0.0;
    u32 cnt = 0;
    #pragma unroll
    for (int r2 = 0; r2 < 25; ++r2) {
        const u32 uu = u[r2];
        if (uu > thr_bits) { ssum += (double)__uint_as_float(uu); cnt++; }
    }
    #pragma unroll
    for (int d = 1; d < 64; d <<= 1) {
        ssum += __shfl_xor(ssum, d, 64);
        cnt  += __shfl_xor(cnt,  d, 64);
    }
    if (lane == 0) { dsum[w] = ssum; cred[w] = cnt; }
    __syncthreads();
    if (t == 0) {
        double S = 0.0; u32 cg = 0;
        #pragma unroll
        for (int j = 0; j < 16; ++j) { S += dsum[j]; cg += cred[j]; }
        S += (double)(k - (int)cg) * (double)thr;   // ties at threshold value
        blk[b * 4 + 3] = S;
    }
}

// ---------------- k_final: one wave reduces the 64 per-row slots ----------------
__global__ __launch_bounds__(64) void k_final(
    const double* __restrict__ blk,
    const int* __restrict__ num_pos,
    float* __restrict__ out)
{
    const int t = threadIdx.x;   // 64 threads, t == batch row
    double l  = blk[t * 4 + 0];
    double o  = blk[t * 4 + 1];
    double cp = blk[t * 4 + 2];
    double se = blk[t * 4 + 3];
    double n  = (double)num_pos[t];
    #pragma unroll
    for (int d = 1; d < 64; d <<= 1) {
        l  += __shfl_xor(l,  d, 64);
        o  += __shfl_xor(o,  d, 64);
        cp += __shfl_xor(cp, d, 64);
        se += __shfl_xor(se, d, 64);
        n  += __shfl_xor(n,  d, 64);
    }
    if (t == 0) {
        out[0] = (float)(l / n);
        out[1] = (float)((cp + se) / n);
        out[2] = (float)(o / n);
    }
}

extern "C" void kernel_launch(void* const* d_in, const int* in_sizes, int n_in,
                              void* d_out, int out_size, void* d_ws, size_t ws_size,
                              hipStream_t stream) {
    const float* loc_data  = (const float*)d_in[0];
    const float* conf_data = (const float*)d_in[1];
    const float* occ_data  = (const float*)d_in[2];
    const float* loc_t     = (const float*)d_in[3];
    const int*   conf_t    = (const int*)d_in[4];
    const float* occ_t     = (const float*)d_in[5];

    char* ws = (char*)d_ws;
    int*    numpos = (int*)ws;               // 64 ints
    double* blk    = (double*)(ws + 256);    // 64*4 doubles
    float*  mine   = (float*)(ws + 4096);    // ROWS floats

    k_main<<<NBLK, 256, 0, stream>>>(conf_data, conf_t, mine);
    k_select<<<BB, 1024, 0, stream>>>(mine, conf_t, loc_data, loc_t,
                                      occ_data, occ_t, blk, numpos);
    k_final<<<1, 64, 0, stream>>>(blk, numpos, (float*)d_out);
}